// Round 18
// baseline (548.767 us; speedup 1.0000x reference)
//
#include <hip/hip_runtime.h>
#include <float.h>

typedef _Float16 f16;
typedef f16 f16x8 __attribute__((ext_vector_type(8)));
typedef float f32x4 __attribute__((ext_vector_type(4)));
typedef unsigned int u32;

#define NPTS 262144
#define DDIM 128
#define NVQ 6
#define KCODES 512
#define TM 64
#define BLOCKT 256

#define GLD16(gp, lp)                                                          \
    __builtin_amdgcn_global_load_lds(                                          \
        (const __attribute__((address_space(1))) void*)(gp),                   \
        (__attribute__((address_space(3))) void*)(lp), 16, 0, 0)

__device__ __forceinline__ int swz(int row, int grp) {
    return row * DDIM + ((grp ^ (row & 7)) << 3);
}
__device__ __forceinline__ u32 umin32(u32 a, u32 b) { return a < b ? a : b; }
__device__ __forceinline__ u32 umax32(u32 a, u32 b) { return a > b ? a : b; }

// top-2 insert: k1 >= k2 invariant; key distinct.
//   k1' = max(k1, key);  k2' = med3(k1, k2, key)   [bit-identical to the
//   3-op min/max chain: key>k1 -> med=k1; k1>key>k2 -> key; else k2]
__device__ __forceinline__ void top2_insert(u32& k1, u32& k2, u32 key) {
    u32 ok1 = k1;
    k1 = umax32(ok1, key);
    asm("v_med3_u32 %0, %1, %2, %3" : "=v"(k2) : "v"(ok1), "v"(k2), "v"(key));
}
// top-2 merge of sorted pairs: k2' = max3(k2, o2, min(k1,o1)); k1' = max
__device__ __forceinline__ void top2_merge(u32& k1, u32& k2, u32 o1, u32 o2) {
    u32 lo = umin32(k1, o1);
    k1 = umax32(k1, o1);
    asm("v_max3_u32 %0, %1, %2, %3" : "=v"(k2) : "v"(k2), "v"(o2), "v"(lo));
}

__device__ __forceinline__ f16x8 cvt8(float4 a, float4 b) {
    f16x8 h;
    h[0] = (f16)a.x; h[1] = (f16)a.y; h[2] = (f16)a.z; h[3] = (f16)a.w;
    h[4] = (f16)b.x; h[5] = (f16)b.y; h[6] = (f16)b.z; h[7] = (f16)b.w;
    return h;
}

// ---------------------------------------------------------------------------
__global__ void zero_commit_kernel(float* p) { *p = 0.0f; }

__global__ void norms_kernel(const float* __restrict__ cb, float* __restrict__ norms,
                             float* __restrict__ ascore) {
    int row = blockIdx.x;
    int lane = threadIdx.x;
    const float* r = cb + (size_t)row * DDIM;
    float2 v = *(const float2*)(r + lane * 2);
    float s = v.x * v.x + v.y * v.y;
    #pragma unroll
    for (int m = 32; m >= 1; m >>= 1) s += __shfl_xor(s, m);
    if (lane == 0) { norms[row] = s; ascore[row] = 512.0f - 0.5f * s; }
}

__global__ void preconv_kernel(const float* __restrict__ cb, f16* __restrict__ cb16) {
    size_t base = ((size_t)blockIdx.x * 256 + threadIdx.x) * 8;
    float4 a = *(const float4*)(cb + base);
    float4 b = *(const float4*)(cb + base + 4);
    *(f16x8*)(cb16 + base) = cvt8(a, b);
}

// ---------------------------------------------------------------------------
// Residual VQ — r17 structure EXACTLY (PASSING, 632us rocprof / 547 bench,
// absmax 5.421875, 4 blocks/CU) + med3/max3 integer compression of the
// top-2 machinery (insert 3->2 ops, merges 4->3). Pure integer identities:
// every key/merge result is bit-identical to r17 -> selection unchanged.
// FP ORDER FROZEN: for ks {for j} MFMA chain, ainit = ascore fold (r16),
// rescue summation tree unchanged (r8/r9 lesson: no reorder).
template<bool PRE>
__global__ __launch_bounds__(BLOCKT)
__attribute__((amdgpu_waves_per_eu(4, 4)))
void rvq_kernel(const float* __restrict__ x, const float* __restrict__ cb,
                const f16* __restrict__ cb16, const float* __restrict__ W,
                const float* __restrict__ bias, const float* __restrict__ norms,
                const float* __restrict__ ascore, float* __restrict__ out) {
    __shared__ f16   rh[TM * DDIM];     // 16 KB residual/y fp16, swizzled
    __shared__ f16   ebuf[4][2048];     // 16 KB wave-private A buffer (single)
    __shared__ float as_lds[KCODES];    // 2 KB ascore slice (current stage)
    __shared__ uint2 cand[4][TM];       // 2 KB per-wave top2 keys per point

    const int tid  = threadIdx.x;
    const int wid  = tid >> 6;
    const int lane = tid & 63;
    const int g    = lane >> 4;      // k-group 0..3
    const int li   = lane & 15;      // row/col within 16-tile
    const int p_own = tid >> 2;      // owned point 0..63
    const int q     = tid & 3;       // owned d-quarter
    const int p0    = blockIdx.x * TM;

    const int srow = (lane >> 4);    // staging row group
    const int sgrp = lane & 15;      // staging 16B group

    // ---- x -> r (regs) and rh (fp16 LDS) ----
    float r[32];
    {
        const float* xs = x + (size_t)(p0 + p_own) * DDIM + q * 32;
        #pragma unroll
        for (int k = 0; k < 8; ++k) {
            float4 v = *(const float4*)(xs + 4 * k);
            r[4*k] = v.x; r[4*k+1] = v.y; r[4*k+2] = v.z; r[4*k+3] = v.w;
        }
    }
    #pragma unroll
    for (int k = 0; k < 4; ++k) {
        f16x8 h;
        #pragma unroll
        for (int m = 0; m < 8; ++m) h[m] = (f16)r[8*k+m];
        *(f16x8*)&rh[swz(p_own, q * 4 + k)] = h;
    }

    // ---- pre-loop: as_lds for s=0 + stage-0 chunk-0 A-tile ----
    as_lds[tid]       = ascore[tid];
    as_lds[tid + 256] = ascore[tid + 256];
    if constexpr (PRE) {
        const char* gsb0 = (const char*)cb16 + ((size_t)16 * wid) * (DDIM * 2);
        char* lb = (char*)&ebuf[wid][0];
        #pragma unroll
        for (int it = 0; it < 4; ++it) {
            int row = it * 4 + srow;
            GLD16(gsb0 + row * 256 + ((sgrp ^ (row & 7)) << 4), lb + it * 1024);
        }
    }
    __syncthreads();

    float commit_part = 0.0f;

    #pragma unroll 1
    for (int s = 0; s < NVQ; ++s) {
        u32 k1[4], k2[4];
        #pragma unroll
        for (int j = 0; j < 4; ++j) { k1[j] = 0u; k2[j] = 0u; }

        if constexpr (PRE) {
            const char* gsb = (const char*)cb16 +
                              ((size_t)s * KCODES + 16 * wid) * (DDIM * 2);
            char* lb = (char*)&ebuf[wid][0];

            #pragma unroll 1
            for (int ch = 0; ch < 8; ++ch) {
                asm volatile("s_waitcnt vmcnt(0)" ::: "memory");  // tile ready

                float4 as4 = *(const float4*)&as_lds[ch * 64 + 16 * wid + 4 * g];
                f32x4 ainit;
                ainit[0] = as4.x; ainit[1] = as4.y; ainit[2] = as4.z; ainit[3] = as4.w;
                f32x4 acc[4];
                #pragma unroll
                for (int j = 0; j < 4; ++j) acc[j] = ainit;

                __builtin_amdgcn_s_setprio(1);
                #pragma unroll
                for (int ks = 0; ks < 4; ++ks) {
                    f16x8 Af = *(const f16x8*)(lb + li * 256 +
                                               (((ks * 4 + g) ^ (li & 7)) << 4));
                    #pragma unroll
                    for (int j = 0; j < 4; ++j) {
                        f16x8 Bf = *(const f16x8*)&rh[swz(16 * j + li, ks * 4 + g)];
                        acc[j] = __builtin_amdgcn_mfma_f32_16x16x32_f16(Af, Bf, acc[j], 0, 0, 0);
                    }
                }
                __builtin_amdgcn_s_setprio(0);

                // all ds_reads of this tile retired -> buffer reusable
                asm volatile("s_waitcnt lgkmcnt(0)" ::: "memory");
                if (ch < 7) {
                    #pragma unroll
                    for (int it = 0; it < 4; ++it) {
                        int row = it * 4 + srow;
                        GLD16(gsb + (size_t)(ch + 1) * 16384 + row * 256 +
                                  ((sgrp ^ (row & 7)) << 4),
                              lb + it * 1024);
                    }
                } else if (s < NVQ - 1) {
                    // cross-stage prologue: s+1 chunk 0; lands under tail
                    const char* gsbn = gsb + (size_t)KCODES * DDIM * 2;
                    #pragma unroll
                    for (int it = 0; it < 4; ++it) {
                        int row = it * 4 + srow;
                        GLD16(gsbn + row * 256 + ((sgrp ^ (row & 7)) << 4),
                              lb + it * 1024);
                    }
                }

                const int invc = 511 - (ch * 64 + 16 * wid + 4 * g);
                #pragma unroll
                for (int j = 0; j < 4; ++j) {
                    #pragma unroll
                    for (int reg = 0; reg < 4; ++reg) {
                        u32 key = (__float_as_uint(acc[j][reg]) & 0xFFFFFE00u) |
                                  (u32)(invc - reg);
                        top2_insert(k1[j], k2[j], key);
                    }
                }
            }
        } else {
            // fallback: direct-global path (fp32 cvt), Bf cached per stage
            f16x8 Bf[4][4];
            #pragma unroll
            for (int j = 0; j < 4; ++j)
                #pragma unroll
                for (int ks = 0; ks < 4; ++ks)
                    Bf[j][ks] = *(const f16x8*)&rh[swz(16 * j + li, ks * 4 + g)];
            const float* Ab32 = cb + ((size_t)s * KCODES + 16 * wid + li) * DDIM + g * 8;
            #pragma unroll 2
            for (int ch = 0; ch < 8; ++ch) {
                float4 as4 = *(const float4*)&as_lds[ch * 64 + 16 * wid + 4 * g];
                f32x4 ainit;
                ainit[0] = as4.x; ainit[1] = as4.y; ainit[2] = as4.z; ainit[3] = as4.w;
                f32x4 acc[4];
                #pragma unroll
                for (int j = 0; j < 4; ++j) acc[j] = ainit;
                #pragma unroll
                for (int ks = 0; ks < 4; ++ks) {
                    const float* ap = Ab32 + (size_t)ch * 64 * DDIM + ks * 32;
                    f16x8 Af = cvt8(*(const float4*)ap, *(const float4*)(ap + 4));
                    #pragma unroll
                    for (int j = 0; j < 4; ++j)
                        acc[j] = __builtin_amdgcn_mfma_f32_16x16x32_f16(Af, Bf[j][ks], acc[j], 0, 0, 0);
                }
                const int invc = 511 - (ch * 64 + 16 * wid + 4 * g);
                #pragma unroll
                for (int j = 0; j < 4; ++j) {
                    #pragma unroll
                    for (int reg = 0; reg < 4; ++reg) {
                        u32 key = (__float_as_uint(acc[j][reg]) & 0xFFFFFE00u) |
                                  (u32)(invc - reg);
                        top2_insert(k1[j], k2[j], key);
                    }
                }
            }
        }

        // ---- in-wave top-2 butterfly across k-groups (lanes xor 16, 32) ----
        #pragma unroll
        for (int m = 16; m <= 32; m <<= 1) {
            #pragma unroll
            for (int j = 0; j < 4; ++j) {
                u32 o1 = (u32)__shfl_xor((int)k1[j], m);
                u32 o2 = (u32)__shfl_xor((int)k2[j], m);
                top2_merge(k1[j], k2[j], o1, o2);
            }
        }
        if (lane < 16) {
            #pragma unroll
            for (int j = 0; j < 4; ++j)
                cand[wid][16 * j + li] = make_uint2(k1[j], k2[j]);
        }
        __syncthreads();   // SYNC-B: cand ready; all waves past chunk loop

        // ---- tail: ascore prefetch for s+1 (latency hides under rescue) ----
        float as_n0 = 0.0f, as_n1 = 0.0f;
        if (s < NVQ - 1) {
            as_n0 = ascore[(s + 1) * KCODES + tid];
            as_n1 = ascore[(s + 1) * KCODES + tid + 256];
        }

        // ---- cross-wave merge, redundantly in every thread ----
        uint2 v0 = cand[0][p_own];
        u32 m1 = v0.x, m2 = v0.y;
        #pragma unroll
        for (int w = 1; w < 4; ++w) {
            uint2 vv = cand[w][p_own];
            top2_merge(m1, m2, vv.x, vv.y);
        }
        int c1 = 511 - (int)(m1 & 0x1FFu);
        int c2 = 511 - (int)(m2 & 0x1FFu);

        // ---- exact fp32 rescue on top-2 (registers only) ----
        const float* E1 = cb + (size_t)(s * KCODES + c1) * DDIM + q * 32;
        const float* E2 = cb + (size_t)(s * KCODES + c2) * DDIM + q * 32;
        float dot1 = 0.0f, dot2 = 0.0f;
        #pragma unroll
        for (int k = 0; k < 8; ++k) {
            float4 a = *(const float4*)(E1 + 4 * k);
            dot1 += a.x * r[4*k] + a.y * r[4*k+1] + a.z * r[4*k+2] + a.w * r[4*k+3];
        }
        #pragma unroll
        for (int k = 0; k < 8; ++k) {
            float4 a = *(const float4*)(E2 + 4 * k);
            dot2 += a.x * r[4*k] + a.y * r[4*k+1] + a.z * r[4*k+2] + a.w * r[4*k+3];
        }
        dot1 += __shfl_xor(dot1, 1); dot1 += __shfl_xor(dot1, 2);
        dot2 += __shfl_xor(dot2, 1); dot2 += __shfl_xor(dot2, 2);
        float d1e = fmaf(-2.0f, dot1, norms[s * KCODES + c1]);
        float d2e = fmaf(-2.0f, dot2, norms[s * KCODES + c2]);
        int best = (d2e < d1e || (d2e == d1e && c2 < c1)) ? c2 : c1;

        if (s == 0 && q == 0)
            out[(size_t)NPTS * DDIM + p0 + p_own] = (float)best;

        // ---- exact residual update (regs) + rh rewrite for next stage ----
        {
            const float* Eb = cb + (size_t)(s * KCODES + best) * DDIM + q * 32;
            float cp = 0.0f;
            #pragma unroll
            for (int k = 0; k < 8; ++k) {
                float4 e = *(const float4*)(Eb + 4 * k);
                r[4*k]   -= e.x; r[4*k+1] -= e.y; r[4*k+2] -= e.z; r[4*k+3] -= e.w;
                cp += r[4*k]*r[4*k] + r[4*k+1]*r[4*k+1] + r[4*k+2]*r[4*k+2] + r[4*k+3]*r[4*k+3];
            }
            if (s == 0) commit_part = cp;
        }
        if (s < NVQ - 1) {
            #pragma unroll
            for (int k = 0; k < 4; ++k) {
                f16x8 h;
                #pragma unroll
                for (int m = 0; m < 8; ++m) h[m] = (f16)r[8*k+m];
                *(f16x8*)&rh[swz(p_own, q * 4 + k)] = h;
            }
            // as_lds refill for s+1 (safe: all reads finished before SYNC-B)
            as_lds[tid]       = as_n0;
            as_lds[tid + 256] = as_n1;
        }
        __syncthreads();   // SYNC-C: rh + as_lds published for stage s+1
    }

    // ---- y = x - r_final -> rh ----
    {
        const float* xs = x + (size_t)(p0 + p_own) * DDIM + q * 32;
        #pragma unroll
        for (int k = 0; k < 4; ++k) {
            float4 a = *(const float4*)(xs + 8 * k);
            float4 b = *(const float4*)(xs + 8 * k + 4);
            f16x8 h;
            h[0]=(f16)(a.x - r[8*k+0]); h[1]=(f16)(a.y - r[8*k+1]);
            h[2]=(f16)(a.z - r[8*k+2]); h[3]=(f16)(a.w - r[8*k+3]);
            h[4]=(f16)(b.x - r[8*k+4]); h[5]=(f16)(b.y - r[8*k+5]);
            h[6]=(f16)(b.z - r[8*k+6]); h[7]=(f16)(b.w - r[8*k+7]);
            *(f16x8*)&rh[swz(p_own, q * 4 + k)] = h;
        }
    }
    __syncthreads();

    // ---- final linear: out = y @ W^T + b (W rows streamed from global) ----
    {
        f16x8 Yf[4][4];
        #pragma unroll
        for (int j = 0; j < 4; ++j)
            #pragma unroll
            for (int ks = 0; ks < 4; ++ks)
                Yf[j][ks] = *(const f16x8*)&rh[swz(16 * j + li, ks * 4 + g)];

        #pragma unroll 1
        for (int ch = 0; ch < 2; ++ch) {
            float4 b4 = *(const float4*)(bias + ch * 64 + 16 * wid + 4 * g);
            f32x4 acc[4];
            #pragma unroll
            for (int j = 0; j < 4; ++j) {
                acc[j][0] = b4.x; acc[j][1] = b4.y; acc[j][2] = b4.z; acc[j][3] = b4.w;
            }
            __builtin_amdgcn_s_setprio(1);
            #pragma unroll
            for (int ks = 0; ks < 4; ++ks) {
                const float* wp = W + (size_t)(ch * 64 + 16 * wid + li) * DDIM + ks * 32 + g * 8;
                f16x8 Af = cvt8(*(const float4*)wp, *(const float4*)(wp + 4));
                #pragma unroll
                for (int j = 0; j < 4; ++j)
                    acc[j] = __builtin_amdgcn_mfma_f32_16x16x32_f16(Af, Yf[j][ks], acc[j], 0, 0, 0);
            }
            __builtin_amdgcn_s_setprio(0);
            int obase = ch * 64 + 16 * wid + 4 * g;
            #pragma unroll
            for (int j = 0; j < 4; ++j)
                *(float4*)(out + (size_t)(p0 + 16 * j + li) * DDIM + obase) =
                    make_float4(acc[j][0], acc[j][1], acc[j][2], acc[j][3]);
        }
    }

    // ---- commit loss: wave shuffle-reduce + block atomic ----
    {
        float cp = commit_part;
        #pragma unroll
        for (int m = 1; m <= 32; m <<= 1) cp += __shfl_xor(cp, m);
        __syncthreads();
        float* wsum = (float*)cand;
        if (lane == 0) wsum[wid] = cp;
        __syncthreads();
        if (tid == 0) {
            float t = (wsum[0] + wsum[1]) + (wsum[2] + wsum[3]);
            atomicAdd(out + (size_t)NPTS * DDIM + NPTS,
                      t * (1.0f / ((float)NPTS * (float)DDIM)));
        }
    }
}

// ---------------------------------------------------------------------------
extern "C" void kernel_launch(void* const* d_in, const int* in_sizes, int n_in,
                              void* d_out, int out_size, void* d_ws, size_t ws_size,
                              hipStream_t stream) {
    const float* x    = (const float*)d_in[0];
    const float* cb   = (const float*)d_in[1];
    const float* linw = (const float*)d_in[2];
    const float* linb = (const float*)d_in[3];
    float* out    = (float*)d_out;
    float* norms  = (float*)d_ws;                        // 3072 f
    float* ascore = norms + 4096;                        // 3072 f
    f16*   cb16   = (f16*)((char*)d_ws + 32768);         // 786432 B
    const size_t need = 32768 + (size_t)NVQ * KCODES * DDIM * 2;

    zero_commit_kernel<<<1, 1, 0, stream>>>(out + (size_t)NPTS * DDIM + NPTS);
    norms_kernel<<<NVQ * KCODES, 64, 0, stream>>>(cb, norms, ascore);

    if (ws_size >= need) {
        preconv_kernel<<<(NVQ * KCODES * DDIM) / (256 * 8), 256, 0, stream>>>(cb, cb16);
        rvq_kernel<true><<<NPTS / TM, BLOCKT, 0, stream>>>(x, cb, cb16, linw, linb,
                                                           norms, ascore, out);
    } else {
        rvq_kernel<false><<<NPTS / TM, BLOCKT, 0, stream>>>(x, cb, cb16, linw, linb,
                                                            norms, ascore, out);
    }
}

// Round 19
// 508.301 us; speedup vs baseline: 1.0796x; 1.0796x over previous
//
#include <hip/hip_runtime.h>
#include <float.h>

typedef _Float16 f16;
typedef f16 f16x8 __attribute__((ext_vector_type(8)));
typedef float f32x4 __attribute__((ext_vector_type(4)));
typedef unsigned int u32;

#define NPTS 262144
#define DDIM 128
#define NVQ 6
#define KCODES 512
#define TM 64
#define BLOCKT 256

#define GLD16(gp, lp)                                                          \
    __builtin_amdgcn_global_load_lds(                                          \
        (const __attribute__((address_space(1))) void*)(gp),                   \
        (__attribute__((address_space(3))) void*)(lp), 16, 0, 0)

__device__ __forceinline__ int swz(int row, int grp) {
    return row * DDIM + ((grp ^ (row & 7)) << 3);
}
__device__ __forceinline__ u32 umin32(u32 a, u32 b) { return a < b ? a : b; }
__device__ __forceinline__ u32 umax32(u32 a, u32 b) { return a > b ? a : b; }

// top-2 insert: k1 >= k2 invariant; keys distinct. Bit-identical to the
// 3-op min/max chain (r18-verified).
__device__ __forceinline__ void top2_insert(u32& k1, u32& k2, u32 key) {
    u32 ok1 = k1;
    k1 = umax32(ok1, key);
    asm("v_med3_u32 %0, %1, %2, %3" : "=v"(k2) : "v"(ok1), "v"(k2), "v"(key));
}
__device__ __forceinline__ void top2_merge(u32& k1, u32& k2, u32 o1, u32 o2) {
    u32 lo = umin32(k1, o1);
    k1 = umax32(k1, o1);
    asm("v_max3_u32 %0, %1, %2, %3" : "=v"(k2) : "v"(k2), "v"(o2), "v"(lo));
}

__device__ __forceinline__ f16x8 cvt8(float4 a, float4 b) {
    f16x8 h;
    h[0] = (f16)a.x; h[1] = (f16)a.y; h[2] = (f16)a.z; h[3] = (f16)a.w;
    h[4] = (f16)b.x; h[5] = (f16)b.y; h[6] = (f16)b.z; h[7] = (f16)b.w;
    return h;
}

// stage one 2KB half-tile: h=0 -> global groups 0-7 (ks01), h=1 -> 8-15 (ks23)
// dest linear [row (it2*8+lane>>3)][hgrp (lane&7)]; source pre-swizzled so the
// read-side XOR recovers group (ks&1)*4+g (both-sides rule; bytes == r17/r18).
__device__ __forceinline__ void stage_half(const char* gbase, int h, char* dst, int lane) {
    #pragma unroll
    for (int it2 = 0; it2 < 2; ++it2) {
        int row = it2 * 8 + (lane >> 3);
        int hg  = lane & 7;
        GLD16(gbase + row * 256 + ((h * 8 + (hg ^ (row & 7))) << 4), dst + it2 * 1024);
    }
}

// ---------------------------------------------------------------------------
__global__ void zero_commit_kernel(float* p) { *p = 0.0f; }

__global__ void norms_kernel(const float* __restrict__ cb, float* __restrict__ norms,
                             float* __restrict__ ascore) {
    int row = blockIdx.x;
    int lane = threadIdx.x;
    const float* r = cb + (size_t)row * DDIM;
    float2 v = *(const float2*)(r + lane * 2);
    float s = v.x * v.x + v.y * v.y;
    #pragma unroll
    for (int m = 32; m >= 1; m >>= 1) s += __shfl_xor(s, m);
    if (lane == 0) { norms[row] = s; ascore[row] = 512.0f - 0.5f * s; }
}

__global__ void preconv_kernel(const float* __restrict__ cb, f16* __restrict__ cb16) {
    size_t base = ((size_t)blockIdx.x * 256 + threadIdx.x) * 8;
    float4 a = *(const float4*)(cb + base);
    float4 b = *(const float4*)(cb + base + 4);
    *(f16x8*)(cb16 + base) = cvt8(a, b);
}

// ---------------------------------------------------------------------------
// Residual VQ — r18 numerics EXACTLY (PASSING, absmax 5.421875) with the
// A-stage pipelined at HALF-TILE granularity (in-place, counted vmcnt(2)):
//   buffer0 <- ks01 halves, buffer1 <- ks23 halves (same 16KB ebuf, 4 blk/CU).
//   wait(2)->MFMA ks01->lgkm->refill h0(ch+1)->wait(2)->MFMA ks23->lgkm->
//   refill h1(ch+1)->epilogue. Each refill leads consumption by ~1 half-chunk
//   phase (vs ~epilogue-only in r17) -> exposed L2 latency halved.
//   FIFO proof: outstanding at each wait = {other half:2, just-issued:2};
//   vmcnt(2) completes the needed oldest pair. Only the final (ch7, s=last)
//   wait needs vmcnt(0) (no refill issued).
// FP ORDER FROZEN: ks=0,1,2,3 chain per acc[j]; ainit = ascore fold;
// identical bytes/fragments -> selection unchanged (r8/r9 lesson).
template<bool PRE>
__global__ __launch_bounds__(BLOCKT)
__attribute__((amdgpu_waves_per_eu(4, 4)))
void rvq_kernel(const float* __restrict__ x, const float* __restrict__ cb,
                const f16* __restrict__ cb16, const float* __restrict__ W,
                const float* __restrict__ bias, const float* __restrict__ norms,
                const float* __restrict__ ascore, float* __restrict__ out) {
    __shared__ f16   rh[TM * DDIM];     // 16 KB residual/y fp16, swizzled
    __shared__ f16   ebuf[4][2048];     // 16 KB wave-private A buffer (2 halves)
    __shared__ float as_lds[KCODES];    // 2 KB ascore slice (current stage)
    __shared__ uint2 cand[4][TM];       // 2 KB per-wave top2 keys per point

    const int tid  = threadIdx.x;
    const int wid  = tid >> 6;
    const int lane = tid & 63;
    const int g    = lane >> 4;      // k-group 0..3
    const int li   = lane & 15;      // row/col within 16-tile
    const int p_own = tid >> 2;      // owned point 0..63
    const int q     = tid & 3;       // owned d-quarter
    const int p0    = blockIdx.x * TM;

    // ---- x -> r (regs) and rh (fp16 LDS) ----
    float r[32];
    {
        const float* xs = x + (size_t)(p0 + p_own) * DDIM + q * 32;
        #pragma unroll
        for (int k = 0; k < 8; ++k) {
            float4 v = *(const float4*)(xs + 4 * k);
            r[4*k] = v.x; r[4*k+1] = v.y; r[4*k+2] = v.z; r[4*k+3] = v.w;
        }
    }
    #pragma unroll
    for (int k = 0; k < 4; ++k) {
        f16x8 h;
        #pragma unroll
        for (int m = 0; m < 8; ++m) h[m] = (f16)r[8*k+m];
        *(f16x8*)&rh[swz(p_own, q * 4 + k)] = h;
    }

    // ---- pre-loop: as_lds for s=0 + stage-0 chunk-0 halves ----
    as_lds[tid]       = ascore[tid];
    as_lds[tid + 256] = ascore[tid + 256];
    if constexpr (PRE) {
        const char* gsb0 = (const char*)cb16 + ((size_t)16 * wid) * (DDIM * 2);
        char* lb = (char*)&ebuf[wid][0];
        stage_half(gsb0, 0, lb, lane);
        stage_half(gsb0, 1, lb + 2048, lane);
    }
    __syncthreads();

    float commit_part = 0.0f;

    #pragma unroll 1
    for (int s = 0; s < NVQ; ++s) {
        u32 k1[4], k2[4];
        #pragma unroll
        for (int j = 0; j < 4; ++j) { k1[j] = 0u; k2[j] = 0u; }

        if constexpr (PRE) {
            const char* gsb = (const char*)cb16 +
                              ((size_t)s * KCODES + 16 * wid) * (DDIM * 2);
            const char* gsbn = gsb + (size_t)KCODES * DDIM * 2;
            char* lb = (char*)&ebuf[wid][0];

            #pragma unroll 1
            for (int ch = 0; ch < 8; ++ch) {
                // ---- half0 (ks01) ready: oldest 2 of 4 outstanding ----
                asm volatile("s_waitcnt vmcnt(2)" ::: "memory");

                float4 as4 = *(const float4*)&as_lds[ch * 64 + 16 * wid + 4 * g];
                f32x4 ainit;
                ainit[0] = as4.x; ainit[1] = as4.y; ainit[2] = as4.z; ainit[3] = as4.w;
                f32x4 acc[4];
                #pragma unroll
                for (int j = 0; j < 4; ++j) acc[j] = ainit;

                __builtin_amdgcn_s_setprio(1);
                #pragma unroll
                for (int ks = 0; ks < 2; ++ks) {
                    f16x8 Af = *(const f16x8*)(lb + li * 128 +
                                               (((ks * 4 + g) ^ (li & 7)) << 4));
                    #pragma unroll
                    for (int j = 0; j < 4; ++j) {
                        f16x8 Bf = *(const f16x8*)&rh[swz(16 * j + li, ks * 4 + g)];
                        acc[j] = __builtin_amdgcn_mfma_f32_16x16x32_f16(Af, Bf, acc[j], 0, 0, 0);
                    }
                }
                __builtin_amdgcn_s_setprio(0);
                asm volatile("s_waitcnt lgkmcnt(0)" ::: "memory");  // half0 reads retired
                if (ch < 7)            stage_half(gsb + (size_t)(ch + 1) * 16384, 0, lb, lane);
                else if (s < NVQ - 1)  stage_half(gsbn, 0, lb, lane);

                // ---- half1 (ks23) ready ----
                if (ch == 7 && s == NVQ - 1)
                    asm volatile("s_waitcnt vmcnt(0)" ::: "memory");  // nothing behind it
                else
                    asm volatile("s_waitcnt vmcnt(2)" ::: "memory");

                __builtin_amdgcn_s_setprio(1);
                #pragma unroll
                for (int ks = 2; ks < 4; ++ks) {
                    f16x8 Af = *(const f16x8*)(lb + 2048 + li * 128 +
                                               ((((ks - 2) * 4 + g) ^ (li & 7)) << 4));
                    #pragma unroll
                    for (int j = 0; j < 4; ++j) {
                        f16x8 Bf = *(const f16x8*)&rh[swz(16 * j + li, ks * 4 + g)];
                        acc[j] = __builtin_amdgcn_mfma_f32_16x16x32_f16(Af, Bf, acc[j], 0, 0, 0);
                    }
                }
                __builtin_amdgcn_s_setprio(0);
                asm volatile("s_waitcnt lgkmcnt(0)" ::: "memory");  // half1 reads retired
                if (ch < 7)            stage_half(gsb + (size_t)(ch + 1) * 16384, 1, lb + 2048, lane);
                else if (s < NVQ - 1)  stage_half(gsbn, 1, lb + 2048, lane);

                // ---- epilogue: top-2 inserts (leads next ch's waits) ----
                const int invc = 511 - (ch * 64 + 16 * wid + 4 * g);
                #pragma unroll
                for (int j = 0; j < 4; ++j) {
                    #pragma unroll
                    for (int reg = 0; reg < 4; ++reg) {
                        u32 key = (__float_as_uint(acc[j][reg]) & 0xFFFFFE00u) |
                                  (u32)(invc - reg);
                        top2_insert(k1[j], k2[j], key);
                    }
                }
            }
        } else {
            // fallback: direct-global path (fp32 cvt), Bf cached per stage
            f16x8 Bf[4][4];
            #pragma unroll
            for (int j = 0; j < 4; ++j)
                #pragma unroll
                for (int ks = 0; ks < 4; ++ks)
                    Bf[j][ks] = *(const f16x8*)&rh[swz(16 * j + li, ks * 4 + g)];
            const float* Ab32 = cb + ((size_t)s * KCODES + 16 * wid + li) * DDIM + g * 8;
            #pragma unroll 2
            for (int ch = 0; ch < 8; ++ch) {
                float4 as4 = *(const float4*)&as_lds[ch * 64 + 16 * wid + 4 * g];
                f32x4 ainit;
                ainit[0] = as4.x; ainit[1] = as4.y; ainit[2] = as4.z; ainit[3] = as4.w;
                f32x4 acc[4];
                #pragma unroll
                for (int j = 0; j < 4; ++j) acc[j] = ainit;
                #pragma unroll
                for (int ks = 0; ks < 4; ++ks) {
                    const float* ap = Ab32 + (size_t)ch * 64 * DDIM + ks * 32;
                    f16x8 Af = cvt8(*(const float4*)ap, *(const float4*)(ap + 4));
                    #pragma unroll
                    for (int j = 0; j < 4; ++j)
                        acc[j] = __builtin_amdgcn_mfma_f32_16x16x32_f16(Af, Bf[j][ks], acc[j], 0, 0, 0);
                }
                const int invc = 511 - (ch * 64 + 16 * wid + 4 * g);
                #pragma unroll
                for (int j = 0; j < 4; ++j) {
                    #pragma unroll
                    for (int reg = 0; reg < 4; ++reg) {
                        u32 key = (__float_as_uint(acc[j][reg]) & 0xFFFFFE00u) |
                                  (u32)(invc - reg);
                        top2_insert(k1[j], k2[j], key);
                    }
                }
            }
        }

        // ---- in-wave top-2 butterfly across k-groups (lanes xor 16, 32) ----
        #pragma unroll
        for (int m = 16; m <= 32; m <<= 1) {
            #pragma unroll
            for (int j = 0; j < 4; ++j) {
                u32 o1 = (u32)__shfl_xor((int)k1[j], m);
                u32 o2 = (u32)__shfl_xor((int)k2[j], m);
                top2_merge(k1[j], k2[j], o1, o2);
            }
        }
        if (lane < 16) {
            #pragma unroll
            for (int j = 0; j < 4; ++j)
                cand[wid][16 * j + li] = make_uint2(k1[j], k2[j]);
        }
        __syncthreads();   // SYNC-B: cand ready; all waves past chunk loop

        // ---- tail: ascore prefetch for s+1 (latency hides under rescue) ----
        float as_n0 = 0.0f, as_n1 = 0.0f;
        if (s < NVQ - 1) {
            as_n0 = ascore[(s + 1) * KCODES + tid];
            as_n1 = ascore[(s + 1) * KCODES + tid + 256];
        }

        // ---- cross-wave merge, redundantly in every thread ----
        uint2 v0 = cand[0][p_own];
        u32 m1 = v0.x, m2 = v0.y;
        #pragma unroll
        for (int w = 1; w < 4; ++w) {
            uint2 vv = cand[w][p_own];
            top2_merge(m1, m2, vv.x, vv.y);
        }
        int c1 = 511 - (int)(m1 & 0x1FFu);
        int c2 = 511 - (int)(m2 & 0x1FFu);

        // ---- exact fp32 rescue on top-2 (registers only) ----
        const float* E1 = cb + (size_t)(s * KCODES + c1) * DDIM + q * 32;
        const float* E2 = cb + (size_t)(s * KCODES + c2) * DDIM + q * 32;
        float dot1 = 0.0f, dot2 = 0.0f;
        #pragma unroll
        for (int k = 0; k < 8; ++k) {
            float4 a = *(const float4*)(E1 + 4 * k);
            dot1 += a.x * r[4*k] + a.y * r[4*k+1] + a.z * r[4*k+2] + a.w * r[4*k+3];
        }
        #pragma unroll
        for (int k = 0; k < 8; ++k) {
            float4 a = *(const float4*)(E2 + 4 * k);
            dot2 += a.x * r[4*k] + a.y * r[4*k+1] + a.z * r[4*k+2] + a.w * r[4*k+3];
        }
        dot1 += __shfl_xor(dot1, 1); dot1 += __shfl_xor(dot1, 2);
        dot2 += __shfl_xor(dot2, 1); dot2 += __shfl_xor(dot2, 2);
        float d1e = fmaf(-2.0f, dot1, norms[s * KCODES + c1]);
        float d2e = fmaf(-2.0f, dot2, norms[s * KCODES + c2]);
        int best = (d2e < d1e || (d2e == d1e && c2 < c1)) ? c2 : c1;

        if (s == 0 && q == 0)
            out[(size_t)NPTS * DDIM + p0 + p_own] = (float)best;

        // ---- exact residual update (regs) + rh rewrite for next stage ----
        {
            const float* Eb = cb + (size_t)(s * KCODES + best) * DDIM + q * 32;
            float cp = 0.0f;
            #pragma unroll
            for (int k = 0; k < 8; ++k) {
                float4 e = *(const float4*)(Eb + 4 * k);
                r[4*k]   -= e.x; r[4*k+1] -= e.y; r[4*k+2] -= e.z; r[4*k+3] -= e.w;
                cp += r[4*k]*r[4*k] + r[4*k+1]*r[4*k+1] + r[4*k+2]*r[4*k+2] + r[4*k+3]*r[4*k+3];
            }
            if (s == 0) commit_part = cp;
        }
        if (s < NVQ - 1) {
            #pragma unroll
            for (int k = 0; k < 4; ++k) {
                f16x8 h;
                #pragma unroll
                for (int m = 0; m < 8; ++m) h[m] = (f16)r[8*k+m];
                *(f16x8*)&rh[swz(p_own, q * 4 + k)] = h;
            }
            as_lds[tid]       = as_n0;
            as_lds[tid + 256] = as_n1;
        }
        __syncthreads();   // SYNC-C: rh + as_lds published for stage s+1
    }

    // ---- y = x - r_final -> rh ----
    {
        const float* xs = x + (size_t)(p0 + p_own) * DDIM + q * 32;
        #pragma unroll
        for (int k = 0; k < 4; ++k) {
            float4 a = *(const float4*)(xs + 8 * k);
            float4 b = *(const float4*)(xs + 8 * k + 4);
            f16x8 h;
            h[0]=(f16)(a.x - r[8*k+0]); h[1]=(f16)(a.y - r[8*k+1]);
            h[2]=(f16)(a.z - r[8*k+2]); h[3]=(f16)(a.w - r[8*k+3]);
            h[4]=(f16)(b.x - r[8*k+4]); h[5]=(f16)(b.y - r[8*k+5]);
            h[6]=(f16)(b.z - r[8*k+6]); h[7]=(f16)(b.w - r[8*k+7]);
            *(f16x8*)&rh[swz(p_own, q * 4 + k)] = h;
        }
    }
    __syncthreads();

    // ---- final linear: out = y @ W^T + b (W rows streamed from global) ----
    {
        f16x8 Yf[4][4];
        #pragma unroll
        for (int j = 0; j < 4; ++j)
            #pragma unroll
            for (int ks = 0; ks < 4; ++ks)
                Yf[j][ks] = *(const f16x8*)&rh[swz(16 * j + li, ks * 4 + g)];

        #pragma unroll 1
        for (int ch = 0; ch < 2; ++ch) {
            float4 b4 = *(const float4*)(bias + ch * 64 + 16 * wid + 4 * g);
            f32x4 acc[4];
            #pragma unroll
            for (int j = 0; j < 4; ++j) {
                acc[j][0] = b4.x; acc[j][1] = b4.y; acc[j][2] = b4.z; acc[j][3] = b4.w;
            }
            __builtin_amdgcn_s_setprio(1);
            #pragma unroll
            for (int ks = 0; ks < 4; ++ks) {
                const float* wp = W + (size_t)(ch * 64 + 16 * wid + li) * DDIM + ks * 32 + g * 8;
                f16x8 Af = cvt8(*(const float4*)wp, *(const float4*)(wp + 4));
                #pragma unroll
                for (int j = 0; j < 4; ++j)
                    acc[j] = __builtin_amdgcn_mfma_f32_16x16x32_f16(Af, Yf[j][ks], acc[j], 0, 0, 0);
            }
            __builtin_amdgcn_s_setprio(0);
            int obase = ch * 64 + 16 * wid + 4 * g;
            #pragma unroll
            for (int j = 0; j < 4; ++j)
                *(float4*)(out + (size_t)(p0 + 16 * j + li) * DDIM + obase) =
                    make_float4(acc[j][0], acc[j][1], acc[j][2], acc[j][3]);
        }
    }

    // ---- commit loss: wave shuffle-reduce + block atomic ----
    {
        float cp = commit_part;
        #pragma unroll
        for (int m = 1; m <= 32; m <<= 1) cp += __shfl_xor(cp, m);
        __syncthreads();
        float* wsum = (float*)cand;
        if (lane == 0) wsum[wid] = cp;
        __syncthreads();
        if (tid == 0) {
            float t = (wsum[0] + wsum[1]) + (wsum[2] + wsum[3]);
            atomicAdd(out + (size_t)NPTS * DDIM + NPTS,
                      t * (1.0f / ((float)NPTS * (float)DDIM)));
        }
    }
}

// ---------------------------------------------------------------------------
extern "C" void kernel_launch(void* const* d_in, const int* in_sizes, int n_in,
                              void* d_out, int out_size, void* d_ws, size_t ws_size,
                              hipStream_t stream) {
    const float* x    = (const float*)d_in[0];
    const float* cb   = (const float*)d_in[1];
    const float* linw = (const float*)d_in[2];
    const float* linb = (const float*)d_in[3];
    float* out    = (float*)d_out;
    float* norms  = (float*)d_ws;                        // 3072 f
    float* ascore = norms + 4096;                        // 3072 f
    f16*   cb16   = (f16*)((char*)d_ws + 32768);         // 786432 B
    const size_t need = 32768 + (size_t)NVQ * KCODES * DDIM * 2;

    zero_commit_kernel<<<1, 1, 0, stream>>>(out + (size_t)NPTS * DDIM + NPTS);
    norms_kernel<<<NVQ * KCODES, 64, 0, stream>>>(cb, norms, ascore);

    if (ws_size >= need) {
        preconv_kernel<<<(NVQ * KCODES * DDIM) / (256 * 8), 256, 0, stream>>>(cb, cb16);
        rvq_kernel<true><<<NPTS / TM, BLOCKT, 0, stream>>>(x, cb, cb16, linw, linb,
                                                           norms, ascore, out);
    } else {
        rvq_kernel<false><<<NPTS / TM, BLOCKT, 0, stream>>>(x, cb, cb16, linw, linb,
                                                            norms, ascore, out);
    }
}